// Round 3
// baseline (183.438 us; speedup 1.0000x reference)
//
#include <hip/hip_runtime.h>
#include <math.h>

typedef unsigned short u16;
typedef unsigned int   u32;
typedef __attribute__((ext_vector_type(8))) short bf16x8;
typedef __attribute__((ext_vector_type(4))) float f32x4;
typedef __attribute__((ext_vector_type(4))) u32   u32x4;

#define NB 8
#define NC 512
#define NS 1024
#define NH 8
#define ND 64
#define NG 32
#define CPG 16
#define SCALE_Q 0.18033688f  /* 0.125 * log2(e): softmax runs in exp2 domain */

__device__ __forceinline__ u16 f2bf(float x) {
  u32 u = __builtin_bit_cast(u32, x);
  u = u + 0x7fffu + ((u >> 16) & 1u);
  return (u16)(u >> 16);
}

__device__ __forceinline__ float exp2_fast(float x) {
  float r;
  asm("v_exp_f32 %0, %1" : "=v"(r) : "v"(x));
  return r;
}

__device__ __forceinline__ u32 cvtpk_bf16(float lo, float hi) {
  u32 r;
  asm("v_cvt_pk_bf16_f32 %0, %1, %2" : "=v"(r) : "v"(lo), "v"(hi));
  return r;
}

__device__ __forceinline__ void gll16(void* l, const void* g) {
  __builtin_amdgcn_global_load_lds((const __attribute__((address_space(1))) void*)g,
                                   (__attribute__((address_space(3))) void*)l, 16, 0, 0);
}

__device__ __forceinline__ void drain_vm() {
  asm volatile("s_waitcnt vmcnt(0)" ::: "memory");
}

// ---------------- K0: weight fp32 -> bf16 ----------------
__global__ __launch_bounds__(256) void wconv_kernel(const float* __restrict__ qkvw,
                                                    const float* __restrict__ outw,
                                                    u16* __restrict__ wq,
                                                    u16* __restrict__ wo) {
  int i = (blockIdx.x * 256 + threadIdx.x) * 4;
  const int NQ = 3 * NC * NC;
  const float* src;
  u16* dst;
  int off;
  if (i < NQ) { src = qkvw; dst = wq; off = i; }
  else        { src = outw; dst = wo; off = i - NQ; }
  float4 v = *(const float4*)(src + off);
  u32 lo = (u32)f2bf(v.x) | ((u32)f2bf(v.y) << 16);
  u32 hi = (u32)f2bf(v.z) | ((u32)f2bf(v.w) << 16);
  u32* p = (u32*)(dst + off);
  p[0] = lo; p[1] = hi;
}

// ---------------- K1: GroupNorm -> xnT[b][p][c] bf16 ----------------
__global__ __launch_bounds__(256) void gn_kernel(const float* __restrict__ x,
                                                 const float* __restrict__ gamma,
                                                 const float* __restrict__ beta,
                                                 u16* __restrict__ xnT) {
  __shared__ float red[10];
  const int t = threadIdx.x;
  const int wave = t >> 6, lane = t & 63;
  const int b = blockIdx.x >> 5, g = blockIdx.x & 31;
  const float* xb = x + (size_t)(b * NC + g * CPG) * NS;

  float s = 0.f, ss = 0.f;
#pragma unroll
  for (int i = 0; i < 16; ++i) {
    int idx = t + i * 256;
    float4 v = ((const float4*)xb)[idx];
    s  += (v.x + v.y) + (v.z + v.w);
    ss += (v.x * v.x + v.y * v.y) + (v.z * v.z + v.w * v.w);
  }
#pragma unroll
  for (int m2 = 32; m2; m2 >>= 1) { s += __shfl_xor(s, m2); ss += __shfl_xor(ss, m2); }
  if (lane == 0) { red[wave] = s; red[4 + wave] = ss; }
  __syncthreads();
  if (t == 0) {
    float fs  = (red[0] + red[1]) + (red[2] + red[3]);
    float fss = (red[4] + red[5]) + (red[6] + red[7]);
    float mean = fs * (1.f / 16384.f);
    float var  = fss * (1.f / 16384.f) - mean * mean;
    red[8] = mean;
    red[9] = rsqrtf(fmaxf(var, 0.f) + 1e-5f);
  }
  __syncthreads();
  const float mean = red[8], inv = red[9];
  float gm[CPG], bt[CPG];
#pragma unroll
  for (int ci = 0; ci < CPG; ++ci) {
    float ga = gamma[g * CPG + ci];
    gm[ci] = ga * inv;
    bt[ci] = beta[g * CPG + ci] - mean * inv * ga;
  }
#pragma unroll
  for (int i = 0; i < 4; ++i) {
    int p = t + i * 256;
    u32 pk[8];
#pragma unroll
    for (int ci = 0; ci < CPG; ci += 2) {
      float v0 = xb[(size_t)ci * NS + p]       * gm[ci]     + bt[ci];
      float v1 = xb[(size_t)(ci + 1) * NS + p] * gm[ci + 1] + bt[ci + 1];
      pk[ci >> 1] = (u32)f2bf(v0) | ((u32)f2bf(v1) << 16);
    }
    u32* dst = (u32*)(xnT + (size_t)(b * NS + p) * NC + g * CPG);
#pragma unroll
    for (int q2 = 0; q2 < 8; ++q2) dst[q2] = pk[q2];
  }
}

// ---------------- K2: QKV gemm_bt ----------------
__global__ __launch_bounds__(256) void qkv_gemm(const u16* __restrict__ A,
                                                const u16* __restrict__ BT,
                                                const float* __restrict__ bias,
                                                u16* __restrict__ qb,
                                                u16* __restrict__ kb,
                                                u16* __restrict__ vb) {
  __shared__ u16 lds[8192];
  const int t = threadIdx.x, wave = t >> 6, lane = t & 63;
  const int bn = blockIdx.x * 128;
  const int bm = blockIdx.y * 128;
  const int bb = blockIdx.z;
  const u16* Bt = BT + (size_t)bb * NS * NC;
  const int wm = wave >> 1, wn = wave & 1;
  f32x4 zero = {0.f, 0.f, 0.f, 0.f};
  f32x4 acc[4][4];
#pragma unroll
  for (int i = 0; i < 4; ++i)
#pragma unroll
    for (int j = 0; j < 4; ++j) acc[i][j] = zero;

  for (int k0 = 0; k0 < NC; k0 += 32) {
#pragma unroll
    for (int call = 0; call < 2; ++call) {
      int c = call * 256 + t;
      int row = c >> 2;
      int chs = (c & 3) ^ ((c >> 3) & 3);
      char* db = (char*)lds + call * 4096 + wave * 1024;
      gll16(db,        (const void*)(A  + (size_t)(bm + row) * NC + k0 + chs * 8));
      gll16(db + 8192, (const void*)(Bt + (size_t)(bn + row) * NC + k0 + chs * 8));
    }
    drain_vm();
    __syncthreads();
    bf16x8 af[4], bfr[4];
#pragma unroll
    for (int mf = 0; mf < 4; ++mf) {
      int row = wm * 64 + mf * 16 + (lane & 15);
      int cb = ((lane >> 4) * 16) ^ (((row >> 1) & 3) << 4);
      af[mf] = *(const bf16x8*)((const char*)lds + row * 64 + cb);
    }
#pragma unroll
    for (int nf = 0; nf < 4; ++nf) {
      int row = wn * 64 + nf * 16 + (lane & 15);
      int cb = ((lane >> 4) * 16) ^ (((row >> 1) & 3) << 4);
      bfr[nf] = *(const bf16x8*)((const char*)lds + 8192 + row * 64 + cb);
    }
#pragma unroll
    for (int mf = 0; mf < 4; ++mf)
#pragma unroll
      for (int nf = 0; nf < 4; ++nf)
        acc[mf][nf] = __builtin_amdgcn_mfma_f32_16x16x32_bf16(af[mf], bfr[nf], acc[mf][nf], 0, 0, 0);
    __syncthreads();
  }
#pragma unroll
  for (int mf = 0; mf < 4; ++mf) {
#pragma unroll
    for (int j = 0; j < 4; ++j) {
      int o = bm + wm * 64 + mf * 16 + (lane >> 4) * 4 + j;
      int n = o / 192;
      int r = o - n * 192;
      float bv = bias[o];
      size_t hb = (size_t)(bb * NH + n);
#pragma unroll
      for (int nf = 0; nf < 4; ++nf) {
        int p = bn + wn * 64 + nf * 16 + (lane & 15);
        float val = acc[mf][nf][j] + bv;
        if (r < 64)       qb[(hb * NS + p) * ND + r] = f2bf(val * SCALE_Q);
        else if (r < 128) kb[(hb * NS + p) * ND + (r - 64)] = f2bf(val);
        else              vb[(hb * ND + (r - 128)) * NS + p] = f2bf(val);
      }
    }
  }
}

// ---------------- K3: flash attention, barrier-free, swapped QK^T ----------------
// Per block: 4 waves x 16 q-rows. K/V fragments read directly from global
// (K/V per head = 256KB, L2-resident; staging is overhead per m169).
// Swapped S^T = mfma(K_perm, Q): lane holds P^T[kv-slice][q], kv-permuted so the
// PV B-fragment is lane-local (zero cross-lane P traffic).
__global__ __launch_bounds__(256) void attn_kernel(const u16* __restrict__ qbuf,
                                                   const u16* __restrict__ kbuf,
                                                   const u16* __restrict__ vbuf,
                                                   u16* __restrict__ aoT) {
  __shared__ char ldsT[8192];  // 4 waves x 2KB output-transpose patch
  const int t = threadIdx.x, wave = t >> 6, lane = t & 63;
  const int qblk = blockIdx.x;
  const int bn = blockIdx.y;
  const int b = bn >> 3, n = bn & 7;
  const u16* qp = qbuf + (size_t)bn * NS * ND;
  const u16* kp = kbuf + (size_t)bn * NS * ND;
  const u16* vp = vbuf + (size_t)bn * ND * NS;
  const int g = lane >> 4, q = lane & 15;

  // Q as B-operand (col=q, k=channel)
  bf16x8 bq[2];
  {
    int qrow = qblk * 64 + wave * 16 + q;
#pragma unroll
    for (int ksc = 0; ksc < 2; ++ksc)
      bq[ksc] = *(const bf16x8*)(qp + (size_t)qrow * ND + ksc * 32 + g * 8);
  }
  // K-row permutation base: A-row rho=q holds kv = 32*(cf>>1) + 8*(rho>>2) + 4*(cf&1) + (rho&3)
  const int kvbase = 8 * (q >> 2) + (q & 3);

  float m = -1e30f, l = 0.f;
  f32x4 zero = {0.f, 0.f, 0.f, 0.f};
  f32x4 oacc[4];  // O^T[d][q]: col=q, row d = df*16 + 4g + r
#pragma unroll
  for (int df = 0; df < 4; ++df) oacc[df] = zero;

  for (int kb = 0; kb < 16; ++kb) {
    const u16* kt = kp + (size_t)(kb * 64) * ND;
    f32x4 sacc[4];
#pragma unroll
    for (int cf = 0; cf < 4; ++cf) sacc[cf] = zero;
#pragma unroll
    for (int cf = 0; cf < 4; ++cf) {
      int kvr = (cf >> 1) * 32 + (cf & 1) * 4 + kvbase;
      const u16* arow = kt + (size_t)kvr * ND + g * 8;
      bf16x8 ak0 = *(const bf16x8*)(arow);
      bf16x8 ak1 = *(const bf16x8*)(arow + 32);
      sacc[cf] = __builtin_amdgcn_mfma_f32_16x16x32_bf16(ak0, bq[0], sacc[cf], 0, 0, 0);
      sacc[cf] = __builtin_amdgcn_mfma_f32_16x16x32_bf16(ak1, bq[1], sacc[cf], 0, 0, 0);
    }
    // online softmax (exp2 domain; Q pre-scaled). Lane holds 16 kv-samples of row q.
    float mx = fmaxf(fmaxf(fmaxf(sacc[0][0], sacc[0][1]), fmaxf(sacc[0][2], sacc[0][3])),
                     fmaxf(fmaxf(sacc[1][0], sacc[1][1]), fmaxf(sacc[1][2], sacc[1][3])));
    mx = fmaxf(mx, fmaxf(fmaxf(fmaxf(sacc[2][0], sacc[2][1]), fmaxf(sacc[2][2], sacc[2][3])),
                         fmaxf(fmaxf(sacc[3][0], sacc[3][1]), fmaxf(sacc[3][2], sacc[3][3]))));
    mx = fmaxf(mx, __shfl_xor(mx, 16));
    mx = fmaxf(mx, __shfl_xor(mx, 32));
    float mn = fmaxf(m, mx);
    float sc = exp2_fast(m - mn);
    m = mn;
    float p[16];
    float sum = 0.f;
#pragma unroll
    for (int cf = 0; cf < 4; ++cf)
#pragma unroll
      for (int r = 0; r < 4; ++r) {
        float pv = exp2_fast(sacc[cf][r] - mn);
        p[cf * 4 + r] = pv;
        sum += pv;
      }
    sum += __shfl_xor(sum, 16);
    sum += __shfl_xor(sum, 32);
    l = l * sc + sum;
#pragma unroll
    for (int df = 0; df < 4; ++df) {
      f32x4 o2 = oacc[df];
      o2[0] *= sc; o2[1] *= sc; o2[2] *= sc; o2[3] *= sc;
      oacc[df] = o2;
    }
    // pack P^T -> PV B-fragments (lane-local by kv-permutation design)
    bf16x8 pb[2];
#pragma unroll
    for (int ks = 0; ks < 2; ++ks) {
      u32x4 w;
      w[0] = cvtpk_bf16(p[ks * 8 + 0], p[ks * 8 + 1]);
      w[1] = cvtpk_bf16(p[ks * 8 + 2], p[ks * 8 + 3]);
      w[2] = cvtpk_bf16(p[ks * 8 + 4], p[ks * 8 + 5]);
      w[3] = cvtpk_bf16(p[ks * 8 + 6], p[ks * 8 + 7]);
      pb[ks] = __builtin_bit_cast(bf16x8, w);
    }
    // O^T += V^T P^T  (A = V^T rows d, k = kv)
#pragma unroll
    for (int df = 0; df < 4; ++df) {
      const u16* vrow = vp + (size_t)(df * 16 + q) * NS + kb * 64 + g * 8;
      bf16x8 av0 = *(const bf16x8*)(vrow);
      bf16x8 av1 = *(const bf16x8*)(vrow + 32);
      oacc[df] = __builtin_amdgcn_mfma_f32_16x16x32_bf16(av0, pb[0], oacc[df], 0, 0, 0);
      oacc[df] = __builtin_amdgcn_mfma_f32_16x16x32_bf16(av1, pb[1], oacc[df], 0, 0, 0);
    }
  }
  const float inv = 1.f / l;
  // transpose O^T -> O via swizzled wave-private LDS patch, then 16B stores
  char* myT = ldsT + wave * 2048;
#pragma unroll
  for (int df = 0; df < 4; ++df)
#pragma unroll
    for (int h = 0; h < 2; ++h) {
      u32 w = cvtpk_bf16(oacc[df][2 * h] * inv, oacc[df][2 * h + 1] * inv);
      int X = (df * 16 + 4 * g + 2 * h) * 2;
      *(u32*)(myT + q * 128 + (X ^ ((q & 7) << 4))) = w;
    }
  // same-wave DS in-order: no barrier needed
#pragma unroll
  for (int h = 0; h < 2; ++h) {
    int q2 = h * 8 + (lane >> 3);
    int c = lane & 7;
    bf16x8 vrow = *(const bf16x8*)(myT + q2 * 128 + ((c * 16) ^ ((q2 & 7) << 4)));
    int prow = qblk * 64 + wave * 16 + q2;
    *(bf16x8*)(aoT + (size_t)(b * NS + prow) * NC + n * 64 + c * 8) = vrow;
  }
}

// ---------------- K4: out gemm_bt + bias + residual ----------------
__global__ __launch_bounds__(256) void out_gemm(const u16* __restrict__ A,
                                                const u16* __restrict__ BT,
                                                const float* __restrict__ bias,
                                                const float* __restrict__ xres,
                                                float* __restrict__ out) {
  __shared__ u16 lds[8192];
  const int t = threadIdx.x, wave = t >> 6, lane = t & 63;
  const int bn = blockIdx.x * 128;
  const int bm = blockIdx.y * 128;
  const int bb = blockIdx.z;
  const u16* Bt = BT + (size_t)bb * NS * NC;
  const int wm = wave >> 1, wn = wave & 1;
  f32x4 zero = {0.f, 0.f, 0.f, 0.f};
  f32x4 acc[4][4];
#pragma unroll
  for (int i = 0; i < 4; ++i)
#pragma unroll
    for (int j = 0; j < 4; ++j) acc[i][j] = zero;

  for (int k0 = 0; k0 < NC; k0 += 32) {
#pragma unroll
    for (int call = 0; call < 2; ++call) {
      int c = call * 256 + t;
      int row = c >> 2;
      int chs = (c & 3) ^ ((c >> 3) & 3);
      char* db = (char*)lds + call * 4096 + wave * 1024;
      gll16(db,        (const void*)(A  + (size_t)(bm + row) * NC + k0 + chs * 8));
      gll16(db + 8192, (const void*)(Bt + (size_t)(bn + row) * NC + k0 + chs * 8));
    }
    drain_vm();
    __syncthreads();
    bf16x8 af[4], bfr[4];
#pragma unroll
    for (int mf = 0; mf < 4; ++mf) {
      int row = wm * 64 + mf * 16 + (lane & 15);
      int cb = ((lane >> 4) * 16) ^ (((row >> 1) & 3) << 4);
      af[mf] = *(const bf16x8*)((const char*)lds + row * 64 + cb);
    }
#pragma unroll
    for (int nf = 0; nf < 4; ++nf) {
      int row = wn * 64 + nf * 16 + (lane & 15);
      int cb = ((lane >> 4) * 16) ^ (((row >> 1) & 3) << 4);
      bfr[nf] = *(const bf16x8*)((const char*)lds + 8192 + row * 64 + cb);
    }
#pragma unroll
    for (int mf = 0; mf < 4; ++mf)
#pragma unroll
      for (int nf = 0; nf < 4; ++nf)
        acc[mf][nf] = __builtin_amdgcn_mfma_f32_16x16x32_bf16(af[mf], bfr[nf], acc[mf][nf], 0, 0, 0);
    __syncthreads();
  }
#pragma unroll
  for (int mf = 0; mf < 4; ++mf) {
#pragma unroll
    for (int j = 0; j < 4; ++j) {
      int o = bm + wm * 64 + mf * 16 + (lane >> 4) * 4 + j;
      float bv = bias[o];
#pragma unroll
      for (int nf = 0; nf < 4; ++nf) {
        int p = bn + wn * 64 + nf * 16 + (lane & 15);
        size_t idx = (size_t)(bb * NC + o) * NS + p;
        out[idx] = acc[mf][nf][j] + bv + xres[idx];
      }
    }
  }
}

extern "C" void kernel_launch(void* const* d_in, const int* in_sizes, int n_in,
                              void* d_out, int out_size, void* d_ws, size_t ws_size,
                              hipStream_t stream) {
  const float* x     = (const float*)d_in[0];
  const float* gn_w  = (const float*)d_in[1];
  const float* gn_b  = (const float*)d_in[2];
  const float* qkv_w = (const float*)d_in[3];
  const float* qkv_b = (const float*)d_in[4];
  const float* out_w = (const float*)d_in[5];
  const float* out_b = (const float*)d_in[6];
  float* out = (float*)d_out;
  char* ws = (char*)d_ws;

  u16* wq  = (u16*)(ws);
  u16* wo  = (u16*)(ws + 1572864);
  u16* xnT = (u16*)(ws + 2097152);
  u16* kb  = (u16*)(ws + 10485760);
  u16* vb  = (u16*)(ws + 18874368);
  u16* aoT = (u16*)(ws + 2097152);   // overlaps xnT (sequentially dead)
  u16* qb  = (u16*)d_out;            // scratch use of d_out; overwritten by out_gemm

  wconv_kernel<<<dim3(1024), dim3(256), 0, stream>>>(qkv_w, out_w, wq, wo);
  gn_kernel<<<dim3(NB * NG), dim3(256), 0, stream>>>(x, gn_w, gn_b, xnT);
  qkv_gemm<<<dim3(8, 12, NB), dim3(256), 0, stream>>>(wq, xnT, qkv_b, qb, kb, vb);
  attn_kernel<<<dim3(16, NB * NH), dim3(256), 0, stream>>>(qb, kb, vb, aoT);
  out_gemm<<<dim3(8, 4, NB), dim3(256), 0, stream>>>(wo, aoT, out_b, x, out);
}

// Round 4
// 101.665 us; speedup vs baseline: 1.8043x; 1.8043x over previous
//
#include <hip/hip_runtime.h>
#include <math.h>

typedef unsigned short u16;
typedef unsigned int   u32;
typedef __attribute__((ext_vector_type(8))) short bf16x8;
typedef __attribute__((ext_vector_type(4))) float f32x4;
typedef __attribute__((ext_vector_type(4))) u32   u32x4;

#define NB 8
#define NC 512
#define NS 1024
#define NH 8
#define ND 64
#define NG 32
#define CPG 16
#define SCALE_Q 0.18033688f  /* 0.125 * log2(e): softmax runs in exp2 domain */

__device__ __forceinline__ u16 f2bf(float x) {
  u32 u = __builtin_bit_cast(u32, x);
  u = u + 0x7fffu + ((u >> 16) & 1u);
  return (u16)(u >> 16);
}

__device__ __forceinline__ float exp2_fast(float x) {
  float r;
  asm("v_exp_f32 %0, %1" : "=v"(r) : "v"(x));
  return r;
}

__device__ __forceinline__ u32 cvtpk_bf16(float lo, float hi) {
  u32 r;
  asm("v_cvt_pk_bf16_f32 %0, %1, %2" : "=v"(r) : "v"(lo), "v"(hi));
  return r;
}

__device__ __forceinline__ void gll16(void* l, const void* g) {
  __builtin_amdgcn_global_load_lds((const __attribute__((address_space(1))) void*)g,
                                   (__attribute__((address_space(3))) void*)l, 16, 0, 0);
}

__device__ __forceinline__ void drain_vm() {
  asm volatile("s_waitcnt vmcnt(0)" ::: "memory");
}

// ---------------- K0: weight fp32 -> bf16 ----------------
__global__ __launch_bounds__(256) void wconv_kernel(const float* __restrict__ qkvw,
                                                    const float* __restrict__ outw,
                                                    u16* __restrict__ wq,
                                                    u16* __restrict__ wo) {
  int i = (blockIdx.x * 256 + threadIdx.x) * 4;
  const int NQ = 3 * NC * NC;
  const float* src;
  u16* dst;
  int off;
  if (i < NQ) { src = qkvw; dst = wq; off = i; }
  else        { src = outw; dst = wo; off = i - NQ; }
  float4 v = *(const float4*)(src + off);
  u32 lo = (u32)f2bf(v.x) | ((u32)f2bf(v.y) << 16);
  u32 hi = (u32)f2bf(v.z) | ((u32)f2bf(v.w) << 16);
  u32* p = (u32*)(dst + off);
  p[0] = lo; p[1] = hi;
}

// ---------------- K1: GroupNorm -> xnT[b][p][c] bf16 ----------------
__global__ __launch_bounds__(256) void gn_kernel(const float* __restrict__ x,
                                                 const float* __restrict__ gamma,
                                                 const float* __restrict__ beta,
                                                 u16* __restrict__ xnT) {
  __shared__ float red[10];
  const int t = threadIdx.x;
  const int wave = t >> 6, lane = t & 63;
  const int b = blockIdx.x >> 5, g = blockIdx.x & 31;
  const float* xb = x + (size_t)(b * NC + g * CPG) * NS;

  float s = 0.f, ss = 0.f;
#pragma unroll
  for (int i = 0; i < 16; ++i) {
    int idx = t + i * 256;
    float4 v = ((const float4*)xb)[idx];
    s  += (v.x + v.y) + (v.z + v.w);
    ss += (v.x * v.x + v.y * v.y) + (v.z * v.z + v.w * v.w);
  }
#pragma unroll
  for (int m2 = 32; m2; m2 >>= 1) { s += __shfl_xor(s, m2); ss += __shfl_xor(ss, m2); }
  if (lane == 0) { red[wave] = s; red[4 + wave] = ss; }
  __syncthreads();
  if (t == 0) {
    float fs  = (red[0] + red[1]) + (red[2] + red[3]);
    float fss = (red[4] + red[5]) + (red[6] + red[7]);
    float mean = fs * (1.f / 16384.f);
    float var  = fss * (1.f / 16384.f) - mean * mean;
    red[8] = mean;
    red[9] = rsqrtf(fmaxf(var, 0.f) + 1e-5f);
  }
  __syncthreads();
  const float mean = red[8], inv = red[9];
  float gm[CPG], bt[CPG];
#pragma unroll
  for (int ci = 0; ci < CPG; ++ci) {
    float ga = gamma[g * CPG + ci];
    gm[ci] = ga * inv;
    bt[ci] = beta[g * CPG + ci] - mean * inv * ga;
  }
#pragma unroll
  for (int i = 0; i < 4; ++i) {
    int p = t + i * 256;
    u32 pk[8];
#pragma unroll
    for (int ci = 0; ci < CPG; ci += 2) {
      float v0 = xb[(size_t)ci * NS + p]       * gm[ci]     + bt[ci];
      float v1 = xb[(size_t)(ci + 1) * NS + p] * gm[ci + 1] + bt[ci + 1];
      pk[ci >> 1] = (u32)f2bf(v0) | ((u32)f2bf(v1) << 16);
    }
    u32* dst = (u32*)(xnT + (size_t)(b * NS + p) * NC + g * CPG);
#pragma unroll
    for (int q2 = 0; q2 < 8; ++q2) dst[q2] = pk[q2];
  }
}

// ---------------- K2: QKV gemm_bt ----------------
__global__ __launch_bounds__(256) void qkv_gemm(const u16* __restrict__ A,
                                                const u16* __restrict__ BT,
                                                const float* __restrict__ bias,
                                                u16* __restrict__ qb,
                                                u16* __restrict__ kb,
                                                u16* __restrict__ vb) {
  __shared__ u16 lds[8192];
  const int t = threadIdx.x, wave = t >> 6, lane = t & 63;
  const int bn = blockIdx.x * 128;
  const int bm = blockIdx.y * 128;
  const int bb = blockIdx.z;
  const u16* Bt = BT + (size_t)bb * NS * NC;
  const int wm = wave >> 1, wn = wave & 1;
  f32x4 zero = {0.f, 0.f, 0.f, 0.f};
  f32x4 acc[4][4];
#pragma unroll
  for (int i = 0; i < 4; ++i)
#pragma unroll
    for (int j = 0; j < 4; ++j) acc[i][j] = zero;

  for (int k0 = 0; k0 < NC; k0 += 32) {
#pragma unroll
    for (int call = 0; call < 2; ++call) {
      int c = call * 256 + t;
      int row = c >> 2;
      int chs = (c & 3) ^ ((c >> 3) & 3);
      char* db = (char*)lds + call * 4096 + wave * 1024;
      gll16(db,        (const void*)(A  + (size_t)(bm + row) * NC + k0 + chs * 8));
      gll16(db + 8192, (const void*)(Bt + (size_t)(bn + row) * NC + k0 + chs * 8));
    }
    drain_vm();
    __syncthreads();
    bf16x8 af[4], bfr[4];
#pragma unroll
    for (int mf = 0; mf < 4; ++mf) {
      int row = wm * 64 + mf * 16 + (lane & 15);
      int cb = ((lane >> 4) * 16) ^ (((row >> 1) & 3) << 4);
      af[mf] = *(const bf16x8*)((const char*)lds + row * 64 + cb);
    }
#pragma unroll
    for (int nf = 0; nf < 4; ++nf) {
      int row = wn * 64 + nf * 16 + (lane & 15);
      int cb = ((lane >> 4) * 16) ^ (((row >> 1) & 3) << 4);
      bfr[nf] = *(const bf16x8*)((const char*)lds + 8192 + row * 64 + cb);
    }
#pragma unroll
    for (int mf = 0; mf < 4; ++mf)
#pragma unroll
      for (int nf = 0; nf < 4; ++nf)
        acc[mf][nf] = __builtin_amdgcn_mfma_f32_16x16x32_bf16(af[mf], bfr[nf], acc[mf][nf], 0, 0, 0);
    __syncthreads();
  }
#pragma unroll
  for (int mf = 0; mf < 4; ++mf) {
#pragma unroll
    for (int j = 0; j < 4; ++j) {
      int o = bm + wm * 64 + mf * 16 + (lane >> 4) * 4 + j;
      int n = o / 192;
      int r = o - n * 192;
      float bv = bias[o];
      size_t hb = (size_t)(bb * NH + n);
#pragma unroll
      for (int nf = 0; nf < 4; ++nf) {
        int p = bn + wn * 64 + nf * 16 + (lane & 15);
        float val = acc[mf][nf][j] + bv;
        if (r < 64)       qb[(hb * NS + p) * ND + r] = f2bf(val * SCALE_Q);
        else if (r < 128) kb[(hb * NS + p) * ND + (r - 64)] = f2bf(val);
        else              vb[(hb * ND + (r - 128)) * NS + p] = f2bf(val);
      }
    }
  }
}

// ---------------- K3: flash attention ----------------
// 4 waves x 16 q-rows. K staged into LDS PRE-PERMUTED (LDS row l=cf*16+q holds
// K[kvr(q,cf)], kvr = 32*(cf>>1)+4*(cf&1)+8*(q>>2)+(q&3)) so the swapped QK^T
// (S^T = mfma(K,Q), lane-local P -> PV B-frag, validated R3) reads consecutive
// LDS rows (R2's 0-conflict pattern). 2-phase pipeline: stage tile t+1 before
// computing tile t; single __syncthreads per tile drains after ~600cy compute.
__global__ __launch_bounds__(256) void attn_kernel(const u16* __restrict__ qbuf,
                                                   const u16* __restrict__ kbuf,
                                                   const u16* __restrict__ vbuf,
                                                   u16* __restrict__ aoT) {
  __shared__ char lds[32768];  // 2 x (K 8KB + V 8KB)
  const int t = threadIdx.x, wave = t >> 6, lane = t & 63;
  const int qblk = blockIdx.x;
  const int bn = blockIdx.y;
  const int b = bn >> 3, n = bn & 7;
  const u16* qp = qbuf + (size_t)bn * NS * ND;
  const char* kpb = (const char*)(kbuf + (size_t)bn * NS * ND);
  const char* vpb = (const char*)(vbuf + (size_t)bn * ND * NS);
  const int g = lane >> 4, q = lane & 15;

  // Q as B-operand (col=q, k=channel)
  bf16x8 bq0, bq1;
  {
    int qrow = qblk * 64 + wave * 16 + q;
    bq0 = *(const bf16x8*)(qp + (size_t)qrow * ND + g * 8);
    bq1 = *(const bf16x8*)(qp + (size_t)qrow * ND + 32 + g * 8);
  }
  // staging source descriptors (per-thread constants)
  int c0 = t, c1 = 256 + t;
  int lam0 = c0 >> 3, lam1 = c1 >> 3;
  int chs0 = (c0 & 7) ^ (lam0 & 7), chs1 = (c1 & 7) ^ (lam1 & 7);
  int kv0 = ((lam0 >> 5) & 1) * 32 + ((lam0 >> 4) & 1) * 4 + ((lam0 >> 2) & 3) * 8 + (lam0 & 3);
  int kv1 = ((lam1 >> 5) & 1) * 32 + ((lam1 >> 4) & 1) * 4 + ((lam1 >> 2) & 3) * 8 + (lam1 & 3);
  const char* ksrc0 = kpb + kv0 * 128 + chs0 * 16;
  const char* ksrc1 = kpb + kv1 * 128 + chs1 * 16;
  const char* vsrc0 = vpb + lam0 * 2048 + chs0 * 16;
  const char* vsrc1 = vpb + lam1 * 2048 + chs1 * 16;
  // hot-loop LDS read offsets (2 regs + imm offsets)
  const int koffA = q * 128 + (((0 * 4 + g) ^ (q & 7)) << 4);
  const int koffB = q * 128 + (((1 * 4 + g) ^ (q & 7)) << 4);

  float m = -1e30f, l = 0.f;
  f32x4 oacc[4];  // O^T[d][q]: col=q, row d = df*16 + 4g + r
#pragma unroll
  for (int df = 0; df < 4; ++df) oacc[df] = (f32x4){0.f, 0.f, 0.f, 0.f};

  // prologue: stage tile 0 into buffer 0
  {
    gll16(lds + c0 * 16,        ksrc0);
    gll16(lds + c1 * 16,        ksrc1);
    gll16(lds + 8192 + c0 * 16, vsrc0);
    gll16(lds + 8192 + c1 * 16, vsrc1);
  }
  __syncthreads();

  for (int kb = 0; kb < 16; ++kb) {
    const char* cur = lds + ((kb & 1) << 14);
    if (kb < 15) {  // stage tile kb+1 into the other buffer (latency hidden under compute)
      char* nxt = lds + (((kb + 1) & 1) << 14);
      size_t ko = (size_t)(kb + 1) * 8192;
      size_t vo = (size_t)(kb + 1) * 128;
      gll16(nxt + c0 * 16,        ksrc0 + ko);
      gll16(nxt + c1 * 16,        ksrc1 + ko);
      gll16(nxt + 8192 + c0 * 16, vsrc0 + vo);
      gll16(nxt + 8192 + c1 * 16, vsrc1 + vo);
    }
    // ---- QK^T: sacc[cf][r] = S[kv = 32*(cf>>1)+4*(cf&1)+8g+r][q] (exp2 domain)
    f32x4 sacc[4];
#pragma unroll
    for (int cf = 0; cf < 4; ++cf) {
      bf16x8 k0 = *(const bf16x8*)(cur + cf * 2048 + koffA);
      bf16x8 k1 = *(const bf16x8*)(cur + cf * 2048 + koffB);
      f32x4 s0 = __builtin_amdgcn_mfma_f32_16x16x32_bf16(k0, bq0, (f32x4){0.f, 0.f, 0.f, 0.f}, 0, 0, 0);
      sacc[cf] = __builtin_amdgcn_mfma_f32_16x16x32_bf16(k1, bq1, s0, 0, 0, 0);
    }
    // ---- online softmax with defer-max (T13): skip reduce+rescale when growth small
    float mx = fmaxf(fmaxf(fmaxf(sacc[0][0], sacc[0][1]), fmaxf(sacc[0][2], sacc[0][3])),
                     fmaxf(fmaxf(sacc[1][0], sacc[1][1]), fmaxf(sacc[1][2], sacc[1][3])));
    mx = fmaxf(mx, fmaxf(fmaxf(fmaxf(sacc[2][0], sacc[2][1]), fmaxf(sacc[2][2], sacc[2][3])),
                         fmaxf(fmaxf(sacc[3][0], sacc[3][1]), fmaxf(sacc[3][2], sacc[3][3]))));
    if (!__all(mx - m <= 8.f)) {
      float mxr = fmaxf(mx, __shfl_xor(mx, 16));
      mxr = fmaxf(mxr, __shfl_xor(mxr, 32));
      float mn = fmaxf(m, mxr);
      float sc = exp2_fast(m - mn);
      m = mn;
      l *= sc;
#pragma unroll
      for (int df = 0; df < 4; ++df) {
        f32x4 o2 = oacc[df];
        o2[0] *= sc; o2[1] *= sc; o2[2] *= sc; o2[3] *= sc;
        oacc[df] = o2;
      }
    }
#pragma unroll
    for (int cf = 0; cf < 4; ++cf)
#pragma unroll
      for (int r = 0; r < 4; ++r) {
        float pv = exp2_fast(sacc[cf][r] - m);
        sacc[cf][r] = pv;
        l += pv;
      }
    // ---- pack P -> PV B-fragments (lane-local by construction)
    u32x4 w0, w1;
    w0[0] = cvtpk_bf16(sacc[0][0], sacc[0][1]); w0[1] = cvtpk_bf16(sacc[0][2], sacc[0][3]);
    w0[2] = cvtpk_bf16(sacc[1][0], sacc[1][1]); w0[3] = cvtpk_bf16(sacc[1][2], sacc[1][3]);
    w1[0] = cvtpk_bf16(sacc[2][0], sacc[2][1]); w1[1] = cvtpk_bf16(sacc[2][2], sacc[2][3]);
    w1[2] = cvtpk_bf16(sacc[3][0], sacc[3][1]); w1[3] = cvtpk_bf16(sacc[3][2], sacc[3][3]);
    bf16x8 pb0 = __builtin_bit_cast(bf16x8, w0);
    bf16x8 pb1 = __builtin_bit_cast(bf16x8, w1);
    // ---- O^T += V^T P^T (V rows linear in LDS, same offsets as K)
    const char* curv = cur + 8192;
#pragma unroll
    for (int df = 0; df < 4; ++df) {
      bf16x8 v0 = *(const bf16x8*)(curv + df * 2048 + koffA);
      bf16x8 v1 = *(const bf16x8*)(curv + df * 2048 + koffB);
      oacc[df] = __builtin_amdgcn_mfma_f32_16x16x32_bf16(v0, pb0, oacc[df], 0, 0, 0);
      oacc[df] = __builtin_amdgcn_mfma_f32_16x16x32_bf16(v1, pb1, oacc[df], 0, 0, 0);
    }
    __syncthreads();  // drains this wave's stage loads (full compute phase elapsed) + barrier
  }
  // final cross-lane l reduction (deferred across all tiles)
  l += __shfl_xor(l, 16);
  l += __shfl_xor(l, 32);
  const float inv = 1.f / l;
  // transpose O^T -> O via swizzled wave-private LDS patch, then 16B stores.
  // Patch lives in buffer-0 K region: tile 15 computed from buffer 1; all waves
  // passed the tile-14 barrier, so buffer 0 has no pending readers. Same-wave
  // DS ordering covers the write->read below.
  char* myT = lds + wave * 2048;
#pragma unroll
  for (int df = 0; df < 4; ++df)
#pragma unroll
    for (int h = 0; h < 2; ++h) {
      u32 w = cvtpk_bf16(oacc[df][2 * h] * inv, oacc[df][2 * h + 1] * inv);
      int X = (df * 16 + 4 * g + 2 * h) * 2;
      *(u32*)(myT + q * 128 + (X ^ ((q & 7) << 4))) = w;
    }
#pragma unroll
  for (int h = 0; h < 2; ++h) {
    int q2 = h * 8 + (lane >> 3);
    int c = lane & 7;
    bf16x8 vrow = *(const bf16x8*)(myT + q2 * 128 + ((c * 16) ^ ((q2 & 7) << 4)));
    int prow = qblk * 64 + wave * 16 + q2;
    *(bf16x8*)(aoT + (size_t)(b * NS + prow) * NC + n * 64 + c * 8) = vrow;
  }
}

// ---------------- K4: out gemm_bt + bias + residual ----------------
__global__ __launch_bounds__(256) void out_gemm(const u16* __restrict__ A,
                                                const u16* __restrict__ BT,
                                                const float* __restrict__ bias,
                                                const float* __restrict__ xres,
                                                float* __restrict__ out) {
  __shared__ u16 lds[8192];
  const int t = threadIdx.x, wave = t >> 6, lane = t & 63;
  const int bn = blockIdx.x * 128;
  const int bm = blockIdx.y * 128;
  const int bb = blockIdx.z;
  const u16* Bt = BT + (size_t)bb * NS * NC;
  const int wm = wave >> 1, wn = wave & 1;
  f32x4 zero = {0.f, 0.f, 0.f, 0.f};
  f32x4 acc[4][4];
#pragma unroll
  for (int i = 0; i < 4; ++i)
#pragma unroll
    for (int j = 0; j < 4; ++j) acc[i][j] = zero;

  for (int k0 = 0; k0 < NC; k0 += 32) {
#pragma unroll
    for (int call = 0; call < 2; ++call) {
      int c = call * 256 + t;
      int row = c >> 2;
      int chs = (c & 3) ^ ((c >> 3) & 3);
      char* db = (char*)lds + call * 4096 + wave * 1024;
      gll16(db,        (const void*)(A  + (size_t)(bm + row) * NC + k0 + chs * 8));
      gll16(db + 8192, (const void*)(Bt + (size_t)(bn + row) * NC + k0 + chs * 8));
    }
    drain_vm();
    __syncthreads();
    bf16x8 af[4], bfr[4];
#pragma unroll
    for (int mf = 0; mf < 4; ++mf) {
      int row = wm * 64 + mf * 16 + (lane & 15);
      int cb = ((lane >> 4) * 16) ^ (((row >> 1) & 3) << 4);
      af[mf] = *(const bf16x8*)((const char*)lds + row * 64 + cb);
    }
#pragma unroll
    for (int nf = 0; nf < 4; ++nf) {
      int row = wn * 64 + nf * 16 + (lane & 15);
      int cb = ((lane >> 4) * 16) ^ (((row >> 1) & 3) << 4);
      bfr[nf] = *(const bf16x8*)((const char*)lds + 8192 + row * 64 + cb);
    }
#pragma unroll
    for (int mf = 0; mf < 4; ++mf)
#pragma unroll
      for (int nf = 0; nf < 4; ++nf)
        acc[mf][nf] = __builtin_amdgcn_mfma_f32_16x16x32_bf16(af[mf], bfr[nf], acc[mf][nf], 0, 0, 0);
    __syncthreads();
  }
#pragma unroll
  for (int mf = 0; mf < 4; ++mf) {
#pragma unroll
    for (int j = 0; j < 4; ++j) {
      int o = bm + wm * 64 + mf * 16 + (lane >> 4) * 4 + j;
      float bv = bias[o];
#pragma unroll
      for (int nf = 0; nf < 4; ++nf) {
        int p = bn + wn * 64 + nf * 16 + (lane & 15);
        size_t idx = (size_t)(bb * NC + o) * NS + p;
        out[idx] = acc[mf][nf][j] + bv + xres[idx];
      }
    }
  }
}

extern "C" void kernel_launch(void* const* d_in, const int* in_sizes, int n_in,
                              void* d_out, int out_size, void* d_ws, size_t ws_size,
                              hipStream_t stream) {
  const float* x     = (const float*)d_in[0];
  const float* gn_w  = (const float*)d_in[1];
  const float* gn_b  = (const float*)d_in[2];
  const float* qkv_w = (const float*)d_in[3];
  const float* qkv_b = (const float*)d_in[4];
  const float* out_w = (const float*)d_in[5];
  const float* out_b = (const float*)d_in[6];
  float* out = (float*)d_out;
  char* ws = (char*)d_ws;

  u16* wq  = (u16*)(ws);
  u16* wo  = (u16*)(ws + 1572864);
  u16* xnT = (u16*)(ws + 2097152);
  u16* kb  = (u16*)(ws + 10485760);
  u16* vb  = (u16*)(ws + 18874368);
  u16* aoT = (u16*)(ws + 2097152);   // overlaps xnT (sequentially dead)
  u16* qb  = (u16*)d_out;            // scratch use of d_out; overwritten by out_gemm

  wconv_kernel<<<dim3(1024), dim3(256), 0, stream>>>(qkv_w, out_w, wq, wo);
  gn_kernel<<<dim3(NB * NG), dim3(256), 0, stream>>>(x, gn_w, gn_b, xnT);
  qkv_gemm<<<dim3(8, 12, NB), dim3(256), 0, stream>>>(wq, xnT, qkv_b, qb, kb, vb);
  attn_kernel<<<dim3(16, NB * NH), dim3(256), 0, stream>>>(qb, kb, vb, aoT);
  out_gemm<<<dim3(8, 4, NB), dim3(256), 0, stream>>>(wo, aoT, out_b, x, out);
}